// Round 7
// baseline (877.285 us; speedup 1.0000x reference)
//
#include <hip/hip_runtime.h>
#include <stdint.h>

#define BT_ 32768
#define T_ 4096
#define D_ 1024

typedef __bf16 bf16x8 __attribute__((ext_vector_type(8)));
typedef float f32x4 __attribute__((ext_vector_type(4)));
typedef float f32x16 __attribute__((ext_vector_type(16)));

__device__ __forceinline__ float bf2f(uint16_t u) {
  union { uint32_t i; float f; } c; c.i = ((uint32_t)u) << 16; return c.f;
}
__device__ __forceinline__ uint16_t f2bf(float f) {
  union { float fl; uint32_t i; } c; c.fl = f;
  return (uint16_t)((c.i + 0x7fffu + ((c.i >> 16) & 1u)) >> 16);
}
__device__ __forceinline__ void async16(const void* g, void* l) {
  __builtin_amdgcn_global_load_lds((const __attribute__((address_space(1))) void*)g,
                                   (__attribute__((address_space(3))) void*)l, 16, 0, 0);
}
__device__ __forceinline__ float elu1(float v) { return v > 0.0f ? v + 1.0f : __expf(v); }
__device__ __forceinline__ float gelu_t(float t) {
  float u = 0.7978845608028654f * (t + 0.044715f * t * t * t);
  float e = __expf(2.0f * u);
  return 0.5f * t * (2.0f - 2.0f / (e + 1.0f));  // == 0.5*t*(1+tanh(u)), overflow-safe
}

// ---------------- all six 1024x1024 weight transposes in ONE launch (gridDim.z selects)
__global__ __launch_bounds__(256) void transpose_pack6(
    const float* __restrict__ wq, const float* __restrict__ wk,
    const float* __restrict__ wv, const float* __restrict__ w1,
    const float* __restrict__ wo, const float* __restrict__ w2,
    uint16_t* __restrict__ WqkvT, uint16_t* __restrict__ W1T,
    uint16_t* __restrict__ WfinT) {
  const float* in; uint16_t* out; int ostride, ocol;
  switch (blockIdx.z) {
    case 0: in = wq; out = WqkvT;                         ostride = 1024; ocol = 0;    break;
    case 1: in = wk; out = WqkvT + (size_t)1024 * 1024;   ostride = 1024; ocol = 0;    break;
    case 2: in = wv; out = WqkvT + (size_t)2048 * 1024;   ostride = 1024; ocol = 0;    break;
    case 3: in = w1; out = W1T;                           ostride = 1024; ocol = 0;    break;
    case 4: in = wo; out = WfinT;                         ostride = 2048; ocol = 0;    break;
    default: in = w2; out = WfinT;                        ostride = 2048; ocol = 1024; break;
  }
  __shared__ float tile[32][33];
  const int c0 = blockIdx.x * 32, r0 = blockIdx.y * 32;
  const int tx = threadIdx.x & 31, ty = threadIdx.x >> 5;
  #pragma unroll
  for (int i = 0; i < 32; i += 8)
    tile[ty + i][tx] = in[(size_t)(r0 + ty + i) * 1024 + c0 + tx];
  __syncthreads();
  #pragma unroll
  for (int i = 0; i < 32; i += 8)
    out[(size_t)(c0 + ty + i) * ostride + ocol + r0 + tx] = f2bf(tile[tx][ty + i]);
}

__global__ void bias_pack(const float* __restrict__ bq, const float* __restrict__ bk,
                          const float* __restrict__ bv, const float* __restrict__ bo,
                          const float* __restrict__ b2, float* __restrict__ bqkv,
                          float* __restrict__ bfin) {
  int i = blockIdx.x * 256 + threadIdx.x;  // 0..4095
  if (i < 1024) bqkv[i] = bq[i];
  else if (i < 2048) bqkv[i] = bk[i - 1024];
  else if (i < 3072) bqkv[i] = bv[i - 2048];
  else bfin[i - 3072] = bo[i - 3072] + b2[i - 3072];
}

// ---------------- fused double LayerNorm: x -> h (LN1), h -> h2 (LN2 on h, per reference quirk)
__global__ __launch_bounds__(256) void ln_kernel(
    const float* __restrict__ x,
    const float* __restrict__ s1, const float* __restrict__ o1,
    const float* __restrict__ s2, const float* __restrict__ o2,
    uint16_t* __restrict__ h, uint16_t* __restrict__ h2) {
  const int row = blockIdx.x, tid = threadIdx.x;
  __shared__ float red[8];
  const float4 xv = ((const float4*)(x + (size_t)row * D_))[tid];
  float s = xv.x + xv.y + xv.z + xv.w;
  float ss = xv.x * xv.x + xv.y * xv.y + xv.z * xv.z + xv.w * xv.w;
  #pragma unroll
  for (int o = 32; o > 0; o >>= 1) { s += __shfl_down(s, o); ss += __shfl_down(ss, o); }
  if ((tid & 63) == 0) { red[tid >> 6] = s; red[4 + (tid >> 6)] = ss; }
  __syncthreads();
  s = red[0] + red[1] + red[2] + red[3];
  ss = red[4] + red[5] + red[6] + red[7];
  const float mean = s * (1.0f / D_);
  const float rstd = rsqrtf(ss * (1.0f / D_) - mean * mean + 1e-5f);
  const float4 s1v = ((const float4*)s1)[tid];
  const float4 o1v = ((const float4*)o1)[tid];
  float hv0 = (xv.x - mean) * rstd * s1v.x + o1v.x;
  float hv1 = (xv.y - mean) * rstd * s1v.y + o1v.y;
  float hv2 = (xv.z - mean) * rstd * s1v.z + o1v.z;
  float hv3 = (xv.w - mean) * rstd * s1v.w + o1v.w;
  ushort4 hu; hu.x = f2bf(hv0); hu.y = f2bf(hv1); hu.z = f2bf(hv2); hu.w = f2bf(hv3);
  ((ushort4*)(h + (size_t)row * D_))[tid] = hu;
  float sb = hv0 + hv1 + hv2 + hv3;
  float ssb = hv0 * hv0 + hv1 * hv1 + hv2 * hv2 + hv3 * hv3;
  #pragma unroll
  for (int o = 32; o > 0; o >>= 1) { sb += __shfl_down(sb, o); ssb += __shfl_down(ssb, o); }
  __syncthreads();  // everyone done reading red from LN1
  if ((tid & 63) == 0) { red[tid >> 6] = sb; red[4 + (tid >> 6)] = ssb; }
  __syncthreads();
  sb = red[0] + red[1] + red[2] + red[3];
  ssb = red[4] + red[5] + red[6] + red[7];
  const float mean2 = sb * (1.0f / D_);
  const float rstd2 = rsqrtf(ssb * (1.0f / D_) - mean2 * mean2 + 1e-5f);
  const float4 s2v = ((const float4*)s2)[tid];
  const float4 o2v = ((const float4*)o2)[tid];
  ushort4 h2u;
  h2u.x = f2bf((hv0 - mean2) * rstd2 * s2v.x + o2v.x);
  h2u.y = f2bf((hv1 - mean2) * rstd2 * s2v.y + o2v.y);
  h2u.z = f2bf((hv2 - mean2) * rstd2 * s2v.z + o2v.z);
  h2u.w = f2bf((hv3 - mean2) * rstd2 * s2v.w + o2v.w);
  ((ushort4*)(h2 + (size_t)row * D_))[tid] = h2u;
}

// ---------------- 256x256 bf16 GEMM, BK=64, 32x32x16 MFMA, K-half-slot pipeline.
// 512 threads = 8 waves (2M x 4N), per-wave 128x64 output (4 mt x 2 nt of 32x32).
// LDS: [2 dbuf][2 khalf] slots of [128 ldsrows][64] bf16 per matrix (128 KB).
// Paired-row swizzle (R5-verified): global row g, k-chunk kc (8-bf16 units within 32-k slot)
// stored at ldsrow g>>1, chunk (((g&1)<<2)|kc) ^ ((g>>1)&7); staged linear via pre-swizzled src.
// Per K-tile: 4 phases x 8 MFMA(32x32x16); stages spread ph0/ph2; vmcnt(4) at ph1/ph3
// (3-phase issue-to-drain cover; never 0 in steady state).
template <int MODE>
__global__ __launch_bounds__(512, 2) void gemm_kernel(
    const uint16_t* __restrict__ A, int lda,
    const uint16_t* __restrict__ Bt, int K,
    const float* __restrict__ bias,
    const int* __restrict__ labels,
    const float* __restrict__ arck,
    const float* __restrict__ arcv,
    const float* __restrict__ xres,
    uint16_t* __restrict__ obf, int ocol,
    float* __restrict__ ofl) {
  __shared__ __align__(16) uint16_t Al[2][2][128 * 64];
  __shared__ __align__(16) uint16_t Bl[2][2][128 * 64];
  const int tid = threadIdx.x, lane = tid & 63, w = tid >> 6;
  // XCD chunking (bijective, nwg%8==0): each XCD gets contiguous m-major range
  const int oid = blockIdx.y * gridDim.x + blockIdx.x;
  const int nwg = gridDim.x * gridDim.y;
  const int lid = (oid & 7) * (nwg >> 3) + (oid >> 3);
  const int m0 = (lid / gridDim.x) * 256, n0 = (lid % gridDim.x) * 256;
  const int wm = w >> 2, wn = w & 3;
  const int l31 = lane & 31, hi = lane >> 5;

  // staging source precompute (pre-swizzled global, linear LDS dest) -- R5-verified
  const int sr = tid >> 3, sc = tid & 7, scs = sc ^ (sr & 7);
  const size_t aRow = (size_t)(m0 + 2 * sr + (scs >> 2)) * lda + (scs & 3) * 8;
  const size_t bRow = (size_t)(n0 + 2 * sr + (scs >> 2)) * K + (scs & 3) * 8;
  const int dOff = sr * 64 + sc * 8;

  // fragment-read precompute: rr = row>>1 bases; cc per k-quarter (kq) and lane-half (hi)
  const int rrA0 = (wm * 128 + l31) >> 1;   // + mt*16
  const int rrB0 = (wn * 64 + l31) >> 1;    // + nt*16
  const int ge = l31 & 1;
  const int ccA0 = ((ge << 2) | hi) ^ (rrA0 & 7);
  const int ccA1 = ((ge << 2) | (2 | hi)) ^ (rrA0 & 7);
  const int ccB0 = ((ge << 2) | hi) ^ (rrB0 & 7);
  const int ccB1 = ((ge << 2) | (2 | hi)) ^ (rrB0 & 7);

  f32x16 acc[2][4];  // [nt][mt]
  #pragma unroll
  for (int i = 0; i < 2; i++)
    #pragma unroll
    for (int j = 0; j < 4; j++) acc[i][j] = (f32x16){};

#define ST_A(pp, kh, kt) do { \
    const uint16_t* s_ = A + aRow + (kt) + (kh) * 32; \
    async16(s_, &Al[pp][kh][dOff]); \
    async16(s_ + (size_t)128 * lda, &Al[pp][kh][dOff + 4096]); } while (0)
#define ST_B(pp, kh, kt) do { \
    const uint16_t* s_ = Bt + bRow + (kt) + (kh) * 32; \
    async16(s_, &Bl[pp][kh][dOff]); \
    async16(s_ + (size_t)128 * K, &Bl[pp][kh][dOff + 4096]); } while (0)
#define RD_A2(pp, kh, mtb) do { \
    _Pragma("unroll") \
    for (int mr = 0; mr < 2; ++mr) { \
      const int rb_ = (rrA0 + ((mtb) + mr) * 16) * 64; \
      afr[mr][0] = *(const bf16x8*)(&Al[pp][kh][rb_ + ccA0 * 8]); \
      afr[mr][1] = *(const bf16x8*)(&Al[pp][kh][rb_ + ccA1 * 8]); \
    } } while (0)
#define RD_Bm(pp, kh) do { \
    _Pragma("unroll") \
    for (int nt = 0; nt < 2; ++nt) { \
      const int rb_ = (rrB0 + nt * 16) * 64; \
      bfr[nt][0] = *(const bf16x8*)(&Bl[pp][kh][rb_ + ccB0 * 8]); \
      bfr[nt][1] = *(const bf16x8*)(&Bl[pp][kh][rb_ + ccB1 * 8]); \
    } } while (0)
#define MM8(mtb) do { \
    __builtin_amdgcn_s_setprio(1); \
    _Pragma("unroll") \
    for (int nt = 0; nt < 2; ++nt) \
      _Pragma("unroll") \
      for (int mr = 0; mr < 2; ++mr) { \
        acc[nt][(mtb) + mr] = __builtin_amdgcn_mfma_f32_32x32x16_bf16( \
            bfr[nt][0], afr[mr][0], acc[nt][(mtb) + mr], 0, 0, 0); \
        acc[nt][(mtb) + mr] = __builtin_amdgcn_mfma_f32_32x32x16_bf16( \
            bfr[nt][1], afr[mr][1], acc[nt][(mtb) + mr], 0, 0, 0); \
      } \
    __builtin_amdgcn_s_setprio(0); } while (0)
#define BAR __builtin_amdgcn_s_barrier()

  // prologue: stage all 4 half-tiles of tile 0; wait kh0 pair (kh1 stays in flight)
  ST_A(0, 0, 0); ST_B(0, 0, 0); ST_A(0, 1, 0); ST_B(0, 1, 0);
  asm volatile("s_waitcnt vmcnt(4)" ::: "memory");
  BAR;

  const int NT = K >> 6;
  for (int t = 0; t < NT; ++t) {
    const int p = t & 1, kt1 = (t + 1) << 6;
    const bool more = (t + 1 < NT);
    bf16x8 afr[2][2], bfr[2][2];  // [tile][kq]
    // ph0: kh0, mt 0-1; issue kh0(t+1)
    RD_Bm(p, 0); RD_A2(p, 0, 0);
    if (more) { ST_A(p ^ 1, 0, kt1); ST_B(p ^ 1, 0, kt1); }
    BAR; MM8(0); BAR;
    // ph1: kh0, mt 2-3; drain kh1(t) (4 newest = kh0(t+1) stay in flight)
    RD_A2(p, 0, 2);
    if (more) asm volatile("s_waitcnt vmcnt(4)" ::: "memory");
    else      asm volatile("s_waitcnt vmcnt(0)" ::: "memory");
    BAR; MM8(2); BAR;
    // ph2: kh1, mt 0-1; issue kh1(t+1)
    RD_Bm(p, 1); RD_A2(p, 1, 0);
    if (more) { ST_A(p ^ 1, 1, kt1); ST_B(p ^ 1, 1, kt1); }
    BAR; MM8(0); BAR;
    // ph3: kh1, mt 2-3; drain kh0(t+1) (kh1(t+1) stays in flight)
    RD_A2(p, 1, 2);
    if (more) asm volatile("s_waitcnt vmcnt(4)" ::: "memory");
    BAR; MM8(2); BAR;
  }
#undef ST_A
#undef ST_B
#undef RD_A2
#undef RD_Bm
#undef MM8
#undef BAR

  // epilogue (32x32 C-layout, swapped operand): out-row m = base + (lane&31);
  // reg quad rq gives 4 consecutive cols at nt*32 + rq*8 + 4*hi.
  #pragma unroll
  for (int mt = 0; mt < 4; ++mt) {
    const int row = m0 + wm * 128 + mt * 32 + l31;
    int lab = 0;
    if constexpr (MODE == 1) lab = labels[row];
    #pragma unroll
    for (int nt = 0; nt < 2; ++nt) {
      #pragma unroll
      for (int rq = 0; rq < 4; ++rq) {
        const int col0 = n0 + wn * 64 + nt * 32 + rq * 8 + hi * 4;
        const float4 b4 = *(const float4*)(bias + col0);
        float v0 = acc[nt][mt][rq * 4 + 0] + b4.x;
        float v1 = acc[nt][mt][rq * 4 + 1] + b4.y;
        float v2 = acc[nt][mt][rq * 4 + 2] + b4.z;
        float v3 = acc[nt][mt][rq * 4 + 3] + b4.w;
        if constexpr (MODE == 1) {
          if (col0 < 1024) {
            v0 = elu1(v0); v1 = elu1(v1); v2 = elu1(v2); v3 = elu1(v3);
          } else if (col0 < 2048) {
            const float4 ak = *(const float4*)(arck + lab * 64 + (col0 & 63));
            v0 = elu1(v0 + ak.x); v1 = elu1(v1 + ak.y); v2 = elu1(v2 + ak.z); v3 = elu1(v3 + ak.w);
          } else {
            const float4 av = *(const float4*)(arcv + lab * 64 + (col0 & 63));
            v0 += av.x; v1 += av.y; v2 += av.z; v3 += av.w;
          }
          ushort4 u; u.x = f2bf(v0); u.y = f2bf(v1); u.z = f2bf(v2); u.w = f2bf(v3);
          *(ushort4*)(obf + (size_t)row * 3072 + ocol + col0) = u;
        } else if constexpr (MODE == 2) {
          ushort4 u;
          u.x = f2bf(gelu_t(v0)); u.y = f2bf(gelu_t(v1)); u.z = f2bf(gelu_t(v2)); u.w = f2bf(gelu_t(v3));
          *(ushort4*)(obf + (size_t)row * 3072 + ocol + col0) = u;
        } else {
          const float4 xr = *(const float4*)(xres + (size_t)row * 1024 + col0);
          float4 o4; o4.x = v0 + xr.x; o4.y = v1 + xr.y; o4.z = v2 + xr.z; o4.w = v3 + xr.w;
          *(float4*)(ofl + (size_t)row * 1024 + col0) = o4;
        }
      }
    }
  }
}

// ---------------- kv reduction: M[bh][i][j] = sum_t phi(k)[t,i]*v[t,j]; ksum[bh][i] = sum_t phi(k)[t,i]
__global__ __launch_bounds__(256) void kv_kernel(const uint16_t* __restrict__ qkv,
    float* __restrict__ Mst, float* __restrict__ ksum) {
  const int bh = blockIdx.y, sub = blockIdx.x;
  const int b = bh >> 4, hh = bh & 15;
  const int base = b * T_ + sub * 512;
  __shared__ __align__(16) float klds[64 * 64];
  __shared__ __align__(16) float vlds[64 * 64];
  const int tid = threadIdx.x;
  const int ti = tid >> 4, tj = tid & 15;
  const int i0 = ti * 4, j0 = tj * 4;
  float acc[4][4] = {};
  float kacc = 0.f;
  for (int cc = 0; cc < 8; cc++) {
    __syncthreads();
    #pragma unroll
    for (int p = 0; p < 4; p++) {
      const int t = p * 16 + ti;
      const size_t rb = (size_t)(base + cc * 64 + t) * 3072;
      const uint2 ku = *(const uint2*)(qkv + rb + 1024 + hh * 64 + tj * 4);
      const uint2 vu = *(const uint2*)(qkv + rb + 2048 + hh * 64 + tj * 4);
      float* kd = klds + t * 64 + tj * 4;
      kd[0] = bf2f((uint16_t)ku.x); kd[1] = bf2f((uint16_t)(ku.x >> 16));
      kd[2] = bf2f((uint16_t)ku.y); kd[3] = bf2f((uint16_t)(ku.y >> 16));
      float* vd = vlds + t * 64 + tj * 4;
      vd[0] = bf2f((uint16_t)vu.x); vd[1] = bf2f((uint16_t)(vu.x >> 16));
      vd[2] = bf2f((uint16_t)vu.y); vd[3] = bf2f((uint16_t)(vu.y >> 16));
    }
    __syncthreads();
    #pragma unroll 8
    for (int t = 0; t < 64; t++) {
      const f32x4 ka = *(const f32x4*)(klds + t * 64 + i0);
      const f32x4 va = *(const f32x4*)(vlds + t * 64 + j0);
      #pragma unroll
      for (int ii = 0; ii < 4; ii++)
        #pragma unroll
        for (int jj = 0; jj < 4; jj++)
          acc[ii][jj] += ka[ii] * va[jj];
    }
    if (tid < 64) {
      #pragma unroll 8
      for (int t = 0; t < 64; t++) kacc += klds[t * 64 + tid];
    }
  }
  float* Mrow = Mst + (size_t)bh * 4096;
  #pragma unroll
  for (int ii = 0; ii < 4; ii++)
    #pragma unroll
    for (int jj = 0; jj < 4; jj++)
      atomicAdd(Mrow + (i0 + ii) * 64 + j0 + jj, acc[ii][jj]);
  if (tid < 64) atomicAdd(ksum + bh * 64 + tid, kacc);
}

// ---------------- attention apply: a[t, h*64+d] = (sum_k M[bh][d][k]*q[t,k]) / (q[t,:].ksum[bh])
__global__ __launch_bounds__(256) void attn_kernel(const uint16_t* __restrict__ qkv,
    const float* __restrict__ Mst, const float* __restrict__ ksum,
    uint16_t* __restrict__ aout) {
  const int bh = blockIdx.y, chunk = blockIdx.x;
  const int b = bh >> 4, hh = bh & 15;
  const int r0 = b * T_ + chunk * 128;
  __shared__ __align__(16) uint16_t qlds[128 * 64];
  __shared__ __align__(16) uint16_t Mlds[64 * 64];
  __shared__ float rinv[128];
  const int tid = threadIdx.x, lane = tid & 63, w = tid >> 6;
  #pragma unroll
  for (int j = 0; j < 4; j++) {
    const int c = w * 4 + j;
    const int rowl = c * 8 + (lane >> 3);
    async16(qkv + (size_t)(r0 + rowl) * 3072 + hh * 64 + (lane & 7) * 8, qlds + c * 512);
  }
  {
    const float4* Mp = (const float4*)(Mst + (size_t)bh * 4096);
    #pragma unroll
    for (int i = 0; i < 4; i++) {
      const float4 mv = Mp[tid + i * 256];
      ushort4 mu; mu.x = f2bf(mv.x); mu.y = f2bf(mv.y); mu.z = f2bf(mv.z); mu.w = f2bf(mv.w);
      *(ushort4*)(Mlds + (size_t)(tid + i * 256) * 4) = mu;
    }
  }
  const float ksv = ksum[bh * 64 + lane];
  __syncthreads();
  for (int i = 0; i < 32; i++) {
    const int t = w * 32 + i;
    float p = bf2f(qlds[t * 64 + lane]) * ksv;
    #pragma unroll
    for (int o = 32; o > 0; o >>= 1) p += __shfl_xor(p, o);
    if (lane == 0) rinv[t] = 1.0f / p;
  }
  __syncthreads();
  f32x4 acc[4][2];  // acc[ni][mi], swapped-operand
  const f32x4 z4 = {0.f, 0.f, 0.f, 0.f};
  #pragma unroll
  for (int i = 0; i < 4; i++)
    #pragma unroll
    for (int j = 0; j < 2; j++) acc[i][j] = z4;
  #pragma unroll
  for (int ks = 0; ks < 2; ks++) {
    bf16x8 af[2], bfv[4];
    #pragma unroll
    for (int mi = 0; mi < 2; mi++)
      af[mi] = *(const bf16x8*)(qlds + (w * 32 + mi * 16 + (lane & 15)) * 64 + ks * 32 + (lane >> 4) * 8);
    #pragma unroll
    for (int ni = 0; ni < 4; ni++)
      bfv[ni] = *(const bf16x8*)(Mlds + (ni * 16 + (lane & 15)) * 64 + ks * 32 + (lane >> 4) * 8);
    #pragma unroll
    for (int ni = 0; ni < 4; ni++)
      #pragma unroll
      for (int mi = 0; mi < 2; mi++)
        acc[ni][mi] = __builtin_amdgcn_mfma_f32_16x16x32_bf16(bfv[ni], af[mi], acc[ni][mi], 0, 0, 0);
  }
  #pragma unroll
  for (int mi = 0; mi < 2; mi++) {
    const int t = w * 32 + mi * 16 + (lane & 15);
    const float rv = rinv[t];
    #pragma unroll
    for (int ni = 0; ni < 4; ni++) {
      const int d0 = ni * 16 + ((lane >> 4) << 2);
      ushort4 u;
      u.x = f2bf(acc[ni][mi][0] * rv);
      u.y = f2bf(acc[ni][mi][1] * rv);
      u.z = f2bf(acc[ni][mi][2] * rv);
      u.w = f2bf(acc[ni][mi][3] * rv);
      *(ushort4*)(aout + (size_t)(r0 + t) * 3072 + 1024 + hh * 64 + d0) = u;
    }
  }
}

extern "C" void kernel_launch(void* const* d_in, const int* in_sizes, int n_in,
                              void* d_out, int out_size, void* d_ws, size_t ws_size,
                              hipStream_t stream) {
  const float* x     = (const float*)d_in[0];
  const int*   labels= (const int*)d_in[1];
  const float* emb_k = (const float*)d_in[2];
  const float* emb_v = (const float*)d_in[3];
  const float* ln1_s = (const float*)d_in[4];
  const float* ln1_b = (const float*)d_in[5];
  const float* wq = (const float*)d_in[6];
  const float* bq = (const float*)d_in[7];
  const float* wk = (const float*)d_in[8];
  const float* bk = (const float*)d_in[9];
  const float* wv = (const float*)d_in[10];
  const float* bv = (const float*)d_in[11];
  const float* wo = (const float*)d_in[12];
  const float* bo = (const float*)d_in[13];
  const float* ln2_s = (const float*)d_in[14];
  const float* ln2_b = (const float*)d_in[15];
  const float* w1 = (const float*)d_in[16];
  const float* b1 = (const float*)d_in[17];
  const float* w2 = (const float*)d_in[18];
  const float* b2 = (const float*)d_in[19];
  float* out = (float*)d_out;
  char* ws = (char*)d_ws;

  // ws layout (bytes)
  uint16_t* qkv   = (uint16_t*)(ws);                 // [32768][3072] bf16: q|kphi|v, later q|a|g
  uint16_t* WqkvT = (uint16_t*)(ws + 201326592);     // [3072][1024]
  uint16_t* W1T   = (uint16_t*)(ws + 207618048);     // [1024][1024]
  uint16_t* WfinT = (uint16_t*)(ws + 209715200);     // [1024][2048] = [Wo^T | W2^T]
  float*    bqkv  = (float*)(ws + 213909504);        // [3072]
  float*    bfin  = (float*)(ws + 213921792);        // [1024] = bo+b2
  float*    Mst   = (float*)(ws + 213925888);        // [128][64][64]
  float*    ksumb = (float*)(ws + 216023040);        // [128][64]

  // h / h2 live inside d_out (bf16), overwritten by final GEMM
  uint16_t* h  = (uint16_t*)d_out;
  uint16_t* h2 = h + (size_t)BT_ * D_;

  const dim3 b256(256);
  transpose_pack6<<<dim3(32, 32, 6), b256, 0, stream>>>(wq, wk, wv, w1, wo, w2,
      WqkvT, W1T, WfinT);
  bias_pack<<<16, b256, 0, stream>>>(bq, bk, bv, bo, b2, bqkv, bfin);
  hipMemsetAsync(Mst, 0, 2097152 + 32768, stream);

  ln_kernel<<<BT_, b256, 0, stream>>>(x, ln1_s, ln1_b, ln2_s, ln2_b, h, h2);

  const dim3 b512(512);
  // QKV projection + bias + arc embeds + elu+1  -> qkv[.,0:3072]
  gemm_kernel<1><<<dim3(12, 128), b512, 0, stream>>>(h, 1024, WqkvT, 1024, bqkv,
      labels, emb_k, emb_v, nullptr, qkv, 0, nullptr);
  // kv state + ksum
  kv_kernel<<<dim3(8, 128), b256, 0, stream>>>(qkv, Mst, ksumb);
  // attention apply -> a into qkv cols [1024,2048)
  attn_kernel<<<dim3(32, 128), b256, 0, stream>>>(qkv, Mst, ksumb, qkv);
  // FFN1 + gelu -> g into qkv cols [2048,3072)
  gemm_kernel<2><<<dim3(4, 128), b512, 0, stream>>>(h2, 1024, W1T, 1024, b1,
      nullptr, nullptr, nullptr, nullptr, qkv, 2048, nullptr);
  // final: [a|g] @ [Wo;W2] + (bo+b2) + x -> out (f32)
  gemm_kernel<3><<<dim3(4, 128), b512, 0, stream>>>(qkv + 1024, 3072, WfinT, 2048, bfin,
      nullptr, nullptr, nullptr, x, nullptr, 0, out);
}

// Round 8
// 807.267 us; speedup vs baseline: 1.0867x; 1.0867x over previous
//
#include <hip/hip_runtime.h>
#include <stdint.h>

#define BT_ 32768
#define T_ 4096
#define D_ 1024

typedef __bf16 bf16x8 __attribute__((ext_vector_type(8)));
typedef float f32x4 __attribute__((ext_vector_type(4)));

__device__ __forceinline__ float bf2f(uint16_t u) {
  union { uint32_t i; float f; } c; c.i = ((uint32_t)u) << 16; return c.f;
}
__device__ __forceinline__ uint16_t f2bf(float f) {
  union { float fl; uint32_t i; } c; c.fl = f;
  return (uint16_t)((c.i + 0x7fffu + ((c.i >> 16) & 1u)) >> 16);
}
__device__ __forceinline__ void async16(const void* g, void* l) {
  __builtin_amdgcn_global_load_lds((const __attribute__((address_space(1))) void*)g,
                                   (__attribute__((address_space(3))) void*)l, 16, 0, 0);
}
__device__ __forceinline__ float elu1(float v) { return v > 0.0f ? v + 1.0f : __expf(v); }
__device__ __forceinline__ float gelu_t(float t) {
  float u = 0.7978845608028654f * (t + 0.044715f * t * t * t);
  float e = __expf(2.0f * u);
  return 0.5f * t * (2.0f - 2.0f / (e + 1.0f));  // == 0.5*t*(1+tanh(u)), overflow-safe
}

// ---------------- all six 1024x1024 weight transposes in ONE launch (z selects);
// z==3 (w1) folds the ln2 scale: out = bf16(W1[k][n] * s2[k]).
__global__ __launch_bounds__(256) void transpose_pack6(
    const float* __restrict__ wq, const float* __restrict__ wk,
    const float* __restrict__ wv, const float* __restrict__ w1,
    const float* __restrict__ wo, const float* __restrict__ w2,
    const float* __restrict__ s2,
    uint16_t* __restrict__ WbigT, uint16_t* __restrict__ WfinT) {
  const float* in; uint16_t* out; int ostride, ocol; bool scale = false;
  switch (blockIdx.z) {
    case 0: in = wq; out = WbigT;                         ostride = 1024; ocol = 0;    break;
    case 1: in = wk; out = WbigT + (size_t)1024 * 1024;   ostride = 1024; ocol = 0;    break;
    case 2: in = wv; out = WbigT + (size_t)2048 * 1024;   ostride = 1024; ocol = 0;    break;
    case 3: in = w1; out = WbigT + (size_t)3072 * 1024;   ostride = 1024; ocol = 0; scale = true; break;
    case 4: in = wo; out = WfinT;                         ostride = 2048; ocol = 0;    break;
    default: in = w2; out = WfinT;                        ostride = 2048; ocol = 1024; break;
  }
  __shared__ float tile[32][33];
  const int c0 = blockIdx.x * 32, r0 = blockIdx.y * 32;
  const int tx = threadIdx.x & 31, ty = threadIdx.x >> 5;
  #pragma unroll
  for (int i = 0; i < 32; i += 8) {
    float v = in[(size_t)(r0 + ty + i) * 1024 + c0 + tx];
    if (scale) v *= s2[r0 + ty + i];
    tile[ty + i][tx] = v;
  }
  __syncthreads();
  #pragma unroll
  for (int i = 0; i < 32; i += 8)
    out[(size_t)(c0 + ty + i) * ostride + ocol + r0 + tx] = f2bf(tile[tx][ty + i]);
}

__global__ void bias_pack(const float* __restrict__ bq, const float* __restrict__ bk,
                          const float* __restrict__ bv, const float* __restrict__ bo,
                          const float* __restrict__ b2, float* __restrict__ biasAll,
                          float* __restrict__ bfin) {
  int i = blockIdx.x * 256 + threadIdx.x;  // 0..4095
  if (i < 1024) biasAll[i] = bq[i];
  else if (i < 2048) biasAll[i] = bk[i - 1024];
  else if (i < 3072) biasAll[i] = bv[i - 2048];
  else bfin[i - 3072] = bo[i - 3072] + b2[i - 3072];
}

// ---------------- column reductions for the LN2 fold:
// s2w1[n] = sum_k s2[k]*W1[k,n];  biasAll[3072+n] = sum_k o2[k]*W1[k,n] + b1[n]
__global__ __launch_bounds__(256) void colreduce(const float* __restrict__ W1,
    const float* __restrict__ s2, const float* __restrict__ o2,
    const float* __restrict__ b1, float* __restrict__ s2w1,
    float* __restrict__ biasg) {
  const int c = blockIdx.x * 128 + (threadIdx.x & 127);
  const int hh = threadIdx.x >> 7;  // 0 or 1
  float sa = 0.f, sb = 0.f;
  for (int k = hh * 512; k < (hh + 1) * 512; ++k) {
    const float w = W1[(size_t)k * 1024 + c];
    sa += s2[k] * w; sb += o2[k] * w;
  }
  __shared__ float pa[128], pb[128];
  if (hh == 1) { pa[threadIdx.x & 127] = sa; pb[threadIdx.x & 127] = sb; }
  __syncthreads();
  if (hh == 0) {
    s2w1[c] = sa + pa[threadIdx.x];
    biasg[c] = sb + pb[threadIdx.x] + b1[c];
  }
}

// ---------------- LN1: x -> h (bf16); also LN2 stats of h -> r2m2[row] = {rstd2, rstd2*mean2}
__global__ __launch_bounds__(256) void ln_kernel(
    const float* __restrict__ x,
    const float* __restrict__ s1, const float* __restrict__ o1,
    uint16_t* __restrict__ h, float2* __restrict__ r2m2) {
  const int row = blockIdx.x, tid = threadIdx.x;
  __shared__ float red[8];
  const float4 xv = ((const float4*)(x + (size_t)row * D_))[tid];
  float s = xv.x + xv.y + xv.z + xv.w;
  float ss = xv.x * xv.x + xv.y * xv.y + xv.z * xv.z + xv.w * xv.w;
  #pragma unroll
  for (int o = 32; o > 0; o >>= 1) { s += __shfl_down(s, o); ss += __shfl_down(ss, o); }
  if ((tid & 63) == 0) { red[tid >> 6] = s; red[4 + (tid >> 6)] = ss; }
  __syncthreads();
  s = red[0] + red[1] + red[2] + red[3];
  ss = red[4] + red[5] + red[6] + red[7];
  const float mean = s * (1.0f / D_);
  const float rstd = rsqrtf(ss * (1.0f / D_) - mean * mean + 1e-5f);
  const float4 s1v = ((const float4*)s1)[tid];
  const float4 o1v = ((const float4*)o1)[tid];
  float hv0 = (xv.x - mean) * rstd * s1v.x + o1v.x;
  float hv1 = (xv.y - mean) * rstd * s1v.y + o1v.y;
  float hv2 = (xv.z - mean) * rstd * s1v.z + o1v.z;
  float hv3 = (xv.w - mean) * rstd * s1v.w + o1v.w;
  ushort4 hu; hu.x = f2bf(hv0); hu.y = f2bf(hv1); hu.z = f2bf(hv2); hu.w = f2bf(hv3);
  ((ushort4*)(h + (size_t)row * D_))[tid] = hu;
  float sb = hv0 + hv1 + hv2 + hv3;
  float ssb = hv0 * hv0 + hv1 * hv1 + hv2 * hv2 + hv3 * hv3;
  #pragma unroll
  for (int o = 32; o > 0; o >>= 1) { sb += __shfl_down(sb, o); ssb += __shfl_down(ssb, o); }
  __syncthreads();  // red reuse safe
  if ((tid & 63) == 0) { red[tid >> 6] = sb; red[4 + (tid >> 6)] = ssb; }
  __syncthreads();
  if (tid == 0) {
    sb = red[0] + red[1] + red[2] + red[3];
    ssb = red[4] + red[5] + red[6] + red[7];
    const float mean2 = sb * (1.0f / D_);
    const float rstd2 = rsqrtf(ssb * (1.0f / D_) - mean2 * mean2 + 1e-5f);
    r2m2[row] = make_float2(rstd2, rstd2 * mean2);
  }
}

// ---------------- 256x256 bf16 GEMM, BK=64, K-half-slot pipeline (exact R5 core).
// MODE 1: merged QKV+FFN1, N=4096 segments: [q|k|v|g]; MODE 3: final (+bias+x residual) -> f32.
template <int MODE>
__global__ __launch_bounds__(512, 2) void gemm_kernel(
    const uint16_t* __restrict__ A, int lda,
    const uint16_t* __restrict__ Bt, int K,
    const float* __restrict__ bias,
    const int* __restrict__ labels,
    const float* __restrict__ arck,
    const float* __restrict__ arcv,
    const float* __restrict__ s2w1,
    const float2* __restrict__ r2m2,
    const float* __restrict__ xres,
    uint16_t* __restrict__ obf,
    uint16_t* __restrict__ vout,
    float* __restrict__ ofl) {
  __shared__ __align__(16) uint16_t Al[2][2][128 * 64];
  __shared__ __align__(16) uint16_t Bl[2][2][128 * 64];
  const int tid = threadIdx.x, lane = tid & 63, w = tid >> 6;
  const int oid = blockIdx.y * gridDim.x + blockIdx.x;
  const int nwg = gridDim.x * gridDim.y;
  const int lid = (oid & 7) * (nwg >> 3) + (oid >> 3);
  const int m0 = (lid / gridDim.x) * 256, n0 = (lid % gridDim.x) * 256;
  const int wm = w >> 2, wn = w & 3;
  const int fr = lane & 15, fk = lane >> 4;

  const int sr = tid >> 3, sc = tid & 7, scs = sc ^ (sr & 7);
  const size_t aRow = (size_t)(m0 + 2 * sr + (scs >> 2)) * lda + (scs & 3) * 8;
  const size_t bRow = (size_t)(n0 + 2 * sr + (scs >> 2)) * K + (scs & 3) * 8;
  const int dOff = sr * 64 + sc * 8;

  f32x4 acc[4][8];  // [ni][mj]
  const f32x4 z4 = {0.f, 0.f, 0.f, 0.f};
  #pragma unroll
  for (int i = 0; i < 4; i++)
    #pragma unroll
    for (int j = 0; j < 8; j++) acc[i][j] = z4;

#define ST_A(pp, kh, kt) do { \
    const uint16_t* s_ = A + aRow + (kt) + (kh) * 32; \
    async16(s_, &Al[pp][kh][dOff]); \
    async16(s_ + (size_t)128 * lda, &Al[pp][kh][dOff + 4096]); } while (0)
#define ST_B(pp, kh, kt) do { \
    const uint16_t* s_ = Bt + bRow + (kt) + (kh) * 32; \
    async16(s_, &Bl[pp][kh][dOff]); \
    async16(s_ + (size_t)128 * K, &Bl[pp][kh][dOff + 4096]); } while (0)
#define RD_A(pp, kh, ch) do { \
    _Pragma("unroll") \
    for (int mi = 0; mi < 4; ++mi) { \
      const int ml = wm * 128 + (ch) * 64 + mi * 16 + fr; \
      const int rr = ml >> 1; \
      const int cc = ((((ml & 1) << 2) | fk) ^ (rr & 7)); \
      afr[mi] = *(const bf16x8*)(&Al[pp][kh][rr * 64 + cc * 8]); \
    } } while (0)
#define RD_B(pp, kh) do { \
    _Pragma("unroll") \
    for (int ni = 0; ni < 4; ++ni) { \
      const int nl = wn * 64 + ni * 16 + fr; \
      const int rr = nl >> 1; \
      const int cc = ((((nl & 1) << 2) | fk) ^ (rr & 7)); \
      bfr[ni] = *(const bf16x8*)(&Bl[pp][kh][rr * 64 + cc * 8]); \
    } } while (0)
#define MM(ch) do { \
    __builtin_amdgcn_s_setprio(1); \
    _Pragma("unroll") \
    for (int ni = 0; ni < 4; ++ni) \
      _Pragma("unroll") \
      for (int mi = 0; mi < 4; ++mi) \
        acc[ni][(ch) * 4 + mi] = __builtin_amdgcn_mfma_f32_16x16x32_bf16( \
            bfr[ni], afr[mi], acc[ni][(ch) * 4 + mi], 0, 0, 0); \
    __builtin_amdgcn_s_setprio(0); } while (0)
#define BAR __builtin_amdgcn_s_barrier()

  ST_A(0, 0, 0); ST_B(0, 0, 0); ST_A(0, 1, 0); ST_B(0, 1, 0);
  asm volatile("s_waitcnt vmcnt(4)" ::: "memory");
  BAR;

  const int NT = K >> 6;
  for (int t = 0; t < NT; ++t) {
    const int p = t & 1, kt1 = (t + 1) << 6;
    const bool more = (t + 1 < NT);
    bf16x8 afr[4], bfr[4];
    RD_A(p, 0, 0); RD_B(p, 0);
    if (more) ST_A(p ^ 1, 0, kt1);
    BAR; MM(0); BAR;
    RD_A(p, 0, 1);
    if (more) {
      ST_B(p ^ 1, 0, kt1);
      asm volatile("s_waitcnt vmcnt(4)" ::: "memory");
    } else {
      asm volatile("s_waitcnt vmcnt(0)" ::: "memory");
    }
    BAR; MM(1); BAR;
    RD_A(p, 1, 0); RD_B(p, 1);
    if (more) ST_A(p ^ 1, 1, kt1);
    BAR; MM(0); BAR;
    RD_A(p, 1, 1);
    if (more) {
      ST_B(p ^ 1, 1, kt1);
      asm volatile("s_waitcnt vmcnt(4)" ::: "memory");
    }
    BAR; MM(1); BAR;
  }
#undef ST_A
#undef ST_B
#undef RD_A
#undef RD_B
#undef MM
#undef BAR

  // epilogue: lane fr owns row; 4 consecutive cols per reg-quad.
  // MODE 1 segment is block-uniform: seg = n0 >> 10 (0:q, 1:k, 2:v, 3:g).
  const int seg = n0 >> 10;
  #pragma unroll
  for (int mi = 0; mi < 8; ++mi) {
    const int row = m0 + wm * 128 + mi * 16 + fr;
    int lab = 0; float2 rm = make_float2(0.f, 0.f);
    if constexpr (MODE == 1) {
      if (seg == 1 || seg == 2) lab = labels[row];
      if (seg == 3) rm = r2m2[row];
    }
    #pragma unroll
    for (int ni = 0; ni < 4; ++ni) {
      const int col0 = n0 + wn * 64 + ni * 16 + (fk << 2);
      const float4 b4 = *(const float4*)(bias + col0);
      float v0, v1, v2, v3;
      if constexpr (MODE == 1) {
        if (seg == 3) {
          const float4 sw = *(const float4*)(s2w1 + (col0 - 3072));
          v0 = rm.x * acc[ni][mi][0] - rm.y * sw.x + b4.x;
          v1 = rm.x * acc[ni][mi][1] - rm.y * sw.y + b4.y;
          v2 = rm.x * acc[ni][mi][2] - rm.y * sw.z + b4.z;
          v3 = rm.x * acc[ni][mi][3] - rm.y * sw.w + b4.w;
        } else {
          v0 = acc[ni][mi][0] + b4.x; v1 = acc[ni][mi][1] + b4.y;
          v2 = acc[ni][mi][2] + b4.z; v3 = acc[ni][mi][3] + b4.w;
        }
        if (seg == 0) {
          v0 = elu1(v0); v1 = elu1(v1); v2 = elu1(v2); v3 = elu1(v3);
          ushort4 u; u.x = f2bf(v0); u.y = f2bf(v1); u.z = f2bf(v2); u.w = f2bf(v3);
          *(ushort4*)(obf + (size_t)row * 3072 + col0) = u;
        } else if (seg == 1) {
          const float4 ak = *(const float4*)(arck + lab * 64 + (col0 & 63));
          v0 = elu1(v0 + ak.x); v1 = elu1(v1 + ak.y); v2 = elu1(v2 + ak.z); v3 = elu1(v3 + ak.w);
          ushort4 u; u.x = f2bf(v0); u.y = f2bf(v1); u.z = f2bf(v2); u.w = f2bf(v3);
          *(ushort4*)(obf + (size_t)row * 3072 + col0) = u;
        } else if (seg == 2) {
          const float4 av = *(const float4*)(arcv + lab * 64 + (col0 & 63));
          v0 += av.x; v1 += av.y; v2 += av.z; v3 += av.w;
          ushort4 u; u.x = f2bf(v0); u.y = f2bf(v1); u.z = f2bf(v2); u.w = f2bf(v3);
          *(ushort4*)(vout + (size_t)row * 1024 + (col0 - 2048)) = u;
        } else {
          ushort4 u;
          u.x = f2bf(gelu_t(v0)); u.y = f2bf(gelu_t(v1));
          u.z = f2bf(gelu_t(v2)); u.w = f2bf(gelu_t(v3));
          *(ushort4*)(obf + (size_t)row * 3072 + (col0 - 1024)) = u;
        }
      } else {
        v0 = acc[ni][mi][0] + b4.x; v1 = acc[ni][mi][1] + b4.y;
        v2 = acc[ni][mi][2] + b4.z; v3 = acc[ni][mi][3] + b4.w;
        const float4 xr = *(const float4*)(xres + (size_t)row * 1024 + col0);
        float4 o4; o4.x = v0 + xr.x; o4.y = v1 + xr.y; o4.z = v2 + xr.z; o4.w = v3 + xr.w;
        *(float4*)(ofl + (size_t)row * 1024 + col0) = o4;
      }
    }
  }
}

// ---------------- kv reduction: M[bh][i][j] = sum_t phi(k)[t,i]*v[t,j]; ksum[bh][i] = sum_t phi(k)[t,i]
__global__ __launch_bounds__(256) void kv_kernel(const uint16_t* __restrict__ qkv,
    const uint16_t* __restrict__ vbuf,
    float* __restrict__ Mst, float* __restrict__ ksum) {
  const int bh = blockIdx.y, sub = blockIdx.x;
  const int b = bh >> 4, hh = bh & 15;
  const int base = b * T_ + sub * 512;
  __shared__ __align__(16) float klds[64 * 64];
  __shared__ __align__(16) float vlds[64 * 64];
  const int tid = threadIdx.x;
  const int ti = tid >> 4, tj = tid & 15;
  const int i0 = ti * 4, j0 = tj * 4;
  float acc[4][4] = {};
  float kacc = 0.f;
  for (int cc = 0; cc < 8; cc++) {
    __syncthreads();
    #pragma unroll
    for (int p = 0; p < 4; p++) {
      const int t = p * 16 + ti;
      const int grow = base + cc * 64 + t;
      const uint2 ku = *(const uint2*)(qkv + (size_t)grow * 3072 + 1024 + hh * 64 + tj * 4);
      const uint2 vu = *(const uint2*)(vbuf + (size_t)grow * 1024 + hh * 64 + tj * 4);
      float* kd = klds + t * 64 + tj * 4;
      kd[0] = bf2f((uint16_t)ku.x); kd[1] = bf2f((uint16_t)(ku.x >> 16));
      kd[2] = bf2f((uint16_t)ku.y); kd[3] = bf2f((uint16_t)(ku.y >> 16));
      float* vd = vlds + t * 64 + tj * 4;
      vd[0] = bf2f((uint16_t)vu.x); vd[1] = bf2f((uint16_t)(vu.x >> 16));
      vd[2] = bf2f((uint16_t)vu.y); vd[3] = bf2f((uint16_t)(vu.y >> 16));
    }
    __syncthreads();
    #pragma unroll 8
    for (int t = 0; t < 64; t++) {
      const f32x4 ka = *(const f32x4*)(klds + t * 64 + i0);
      const f32x4 va = *(const f32x4*)(vlds + t * 64 + j0);
      #pragma unroll
      for (int ii = 0; ii < 4; ii++)
        #pragma unroll
        for (int jj = 0; jj < 4; jj++)
          acc[ii][jj] += ka[ii] * va[jj];
    }
    if (tid < 64) {
      #pragma unroll 8
      for (int t = 0; t < 64; t++) kacc += klds[t * 64 + tid];
    }
  }
  float* Mrow = Mst + (size_t)bh * 4096;
  #pragma unroll
  for (int ii = 0; ii < 4; ii++)
    #pragma unroll
    for (int jj = 0; jj < 4; jj++)
      atomicAdd(Mrow + (i0 + ii) * 64 + j0 + jj, acc[ii][jj]);
  if (tid < 64) atomicAdd(ksum + bh * 64 + tid, kacc);
}

// ---------------- attention apply: a[t, h*64+d] = (sum_k M[bh][d][k]*q[t,k]) / (q[t,:].ksum[bh])
__global__ __launch_bounds__(256) void attn_kernel(const uint16_t* __restrict__ qkv,
    const float* __restrict__ Mst, const float* __restrict__ ksum,
    uint16_t* __restrict__ aout) {
  const int bh = blockIdx.y, chunk = blockIdx.x;
  const int b = bh >> 4, hh = bh & 15;
  const int r0 = b * T_ + chunk * 128;
  __shared__ __align__(16) uint16_t qlds[128 * 64];
  __shared__ __align__(16) uint16_t Mlds[64 * 64];
  __shared__ float rinv[128];
  const int tid = threadIdx.x, lane = tid & 63, w = tid >> 6;
  #pragma unroll
  for (int j = 0; j < 4; j++) {
    const int c = w * 4 + j;
    const int rowl = c * 8 + (lane >> 3);
    async16(qkv + (size_t)(r0 + rowl) * 3072 + hh * 64 + (lane & 7) * 8, qlds + c * 512);
  }
  {
    const float4* Mp = (const float4*)(Mst + (size_t)bh * 4096);
    #pragma unroll
    for (int i = 0; i < 4; i++) {
      const float4 mv = Mp[tid + i * 256];
      ushort4 mu; mu.x = f2bf(mv.x); mu.y = f2bf(mv.y); mu.z = f2bf(mv.z); mu.w = f2bf(mv.w);
      *(ushort4*)(Mlds + (size_t)(tid + i * 256) * 4) = mu;
    }
  }
  const float ksv = ksum[bh * 64 + lane];
  __syncthreads();
  for (int i = 0; i < 32; i++) {
    const int t = w * 32 + i;
    float p = bf2f(qlds[t * 64 + lane]) * ksv;
    #pragma unroll
    for (int o = 32; o > 0; o >>= 1) p += __shfl_xor(p, o);
    if (lane == 0) rinv[t] = 1.0f / p;
  }
  __syncthreads();
  f32x4 acc[4][2];
  const f32x4 z4 = {0.f, 0.f, 0.f, 0.f};
  #pragma unroll
  for (int i = 0; i < 4; i++)
    #pragma unroll
    for (int j = 0; j < 2; j++) acc[i][j] = z4;
  #pragma unroll
  for (int ks = 0; ks < 2; ks++) {
    bf16x8 af[2], bfv[4];
    #pragma unroll
    for (int mi = 0; mi < 2; mi++)
      af[mi] = *(const bf16x8*)(qlds + (w * 32 + mi * 16 + (lane & 15)) * 64 + ks * 32 + (lane >> 4) * 8);
    #pragma unroll
    for (int ni = 0; ni < 4; ni++)
      bfv[ni] = *(const bf16x8*)(Mlds + (ni * 16 + (lane & 15)) * 64 + ks * 32 + (lane >> 4) * 8);
    #pragma unroll
    for (int ni = 0; ni < 4; ni++)
      #pragma unroll
      for (int mi = 0; mi < 2; mi++)
        acc[ni][mi] = __builtin_amdgcn_mfma_f32_16x16x32_bf16(bfv[ni], af[mi], acc[ni][mi], 0, 0, 0);
  }
  #pragma unroll
  for (int mi = 0; mi < 2; mi++) {
    const int t = w * 32 + mi * 16 + (lane & 15);
    const float rv = rinv[t];
    #pragma unroll
    for (int ni = 0; ni < 4; ni++) {
      const int d0 = ni * 16 + ((lane >> 4) << 2);
      ushort4 u;
      u.x = f2bf(acc[ni][mi][0] * rv);
      u.y = f2bf(acc[ni][mi][1] * rv);
      u.z = f2bf(acc[ni][mi][2] * rv);
      u.w = f2bf(acc[ni][mi][3] * rv);
      *(ushort4*)(aout + (size_t)(r0 + t) * 3072 + 1024 + hh * 64 + d0) = u;
    }
  }
}

extern "C" void kernel_launch(void* const* d_in, const int* in_sizes, int n_in,
                              void* d_out, int out_size, void* d_ws, size_t ws_size,
                              hipStream_t stream) {
  const float* x     = (const float*)d_in[0];
  const int*   labels= (const int*)d_in[1];
  const float* emb_k = (const float*)d_in[2];
  const float* emb_v = (const float*)d_in[3];
  const float* ln1_s = (const float*)d_in[4];
  const float* ln1_b = (const float*)d_in[5];
  const float* wq = (const float*)d_in[6];
  const float* bq = (const float*)d_in[7];
  const float* wk = (const float*)d_in[8];
  const float* bk = (const float*)d_in[9];
  const float* wv = (const float*)d_in[10];
  const float* bv = (const float*)d_in[11];
  const float* wo = (const float*)d_in[12];
  const float* bo = (const float*)d_in[13];
  const float* ln2_s = (const float*)d_in[14];
  const float* ln2_b = (const float*)d_in[15];
  const float* w1 = (const float*)d_in[16];
  const float* b1 = (const float*)d_in[17];
  const float* w2 = (const float*)d_in[18];
  const float* b2 = (const float*)d_in[19];
  float* out = (float*)d_out;
  char* ws = (char*)d_ws;

  // ws layout (bytes)
  uint16_t* qkv    = (uint16_t*)(ws);                 // [32768][3072] bf16: q|kphi|(a)|g
  uint16_t* WbigT  = (uint16_t*)(ws + 201326592);     // [4096][1024] = [Wq|Wk|Wv|W1s]^T
  uint16_t* WfinT  = (uint16_t*)(ws + 209715200);     // [1024][2048] = [Wo^T | W2^T]
  float*    biasAll= (float*)(ws + 213909504);        // [4096]: bq|bk|bv|(o2W1+b1)
  float*    bfin   = (float*)(ws + 213925888);        // [1024] = bo+b2
  float*    s2w1   = (float*)(ws + 213929984);        // [1024]
  float2*   r2m2   = (float2*)(ws + 213934080);       // [32768] {rstd2, rstd2*mean2}
  float*    Mst    = (float*)(ws + 214196224);        // [128][64][64]
  float*    ksumb  = (float*)(ws + 216293376);        // [128][64]

  // h lives in d_out[0:64MB]; v (bf16) in d_out[64MB:128MB]; final GEMM overwrites all.
  uint16_t* h    = (uint16_t*)d_out;
  uint16_t* vbuf = h + (size_t)BT_ * D_;

  const dim3 b256(256);
  transpose_pack6<<<dim3(32, 32, 6), b256, 0, stream>>>(wq, wk, wv, w1, wo, w2,
      ln2_s, WbigT, WfinT);
  bias_pack<<<16, b256, 0, stream>>>(bq, bk, bv, bo, b2, biasAll, bfin);
  colreduce<<<8, b256, 0, stream>>>(w1, ln2_s, ln2_b, b1, s2w1, biasAll + 3072);
  hipMemsetAsync(Mst, 0, 2097152 + 32768, stream);

  ln_kernel<<<BT_, b256, 0, stream>>>(x, ln1_s, ln1_b, h, r2m2);

  const dim3 b512(512);
  // merged QKV + FFN1: [q|k|v|g] = h @ [Wq|Wk|Wv|W1s] with per-segment epilogues
  gemm_kernel<1><<<dim3(16, 128), b512, 0, stream>>>(h, 1024, WbigT, 1024, biasAll,
      labels, emb_k, emb_v, s2w1, r2m2, nullptr, qkv, vbuf, nullptr);
  // kv state + ksum (v from vbuf)
  kv_kernel<<<dim3(8, 128), b256, 0, stream>>>(qkv, vbuf, Mst, ksumb);
  // attention apply -> a into qkv cols [1024,2048)
  attn_kernel<<<dim3(32, 128), b256, 0, stream>>>(qkv, Mst, ksumb, qkv);
  // final: [a|g] @ [Wo;W2] + (bo+b2) + x -> out (f32)
  gemm_kernel<3><<<dim3(4, 128), b512, 0, stream>>>(qkv + 1024, 3072, WfinT, 2048, bfin,
      nullptr, nullptr, nullptr, nullptr, nullptr, x, nullptr, nullptr, out);
}

// Round 9
// 773.135 us; speedup vs baseline: 1.1347x; 1.0441x over previous
//
#include <hip/hip_runtime.h>
#include <stdint.h>

#define BT_ 32768
#define T_ 4096
#define D_ 1024

typedef __bf16 bf16x8 __attribute__((ext_vector_type(8)));
typedef float f32x4 __attribute__((ext_vector_type(4)));

__device__ __forceinline__ float bf2f(uint16_t u) {
  union { uint32_t i; float f; } c; c.i = ((uint32_t)u) << 16; return c.f;
}
__device__ __forceinline__ uint16_t f2bf(float f) {
  union { float fl; uint32_t i; } c; c.fl = f;
  return (uint16_t)((c.i + 0x7fffu + ((c.i >> 16) & 1u)) >> 16);
}
__device__ __forceinline__ void async16(const void* g, void* l) {
  __builtin_amdgcn_global_load_lds((const __attribute__((address_space(1))) void*)g,
                                   (__attribute__((address_space(3))) void*)l, 16, 0, 0);
}
__device__ __forceinline__ float elu1(float v) { return v > 0.0f ? v + 1.0f : __expf(v); }
__device__ __forceinline__ float gelu_t(float t) {
  float u = 0.7978845608028654f * (t + 0.044715f * t * t * t);
  float e = __expf(2.0f * u);
  return 0.5f * t * (2.0f - 2.0f / (e + 1.0f));  // == 0.5*t*(1+tanh(u)), overflow-safe
}

// ---------------- all six 1024x1024 weight transposes in ONE launch (z selects);
// z==3 (w1) folds the ln2 scale: out = bf16(W1[k][n] * s2[k]).
__global__ __launch_bounds__(256) void transpose_pack6(
    const float* __restrict__ wq, const float* __restrict__ wk,
    const float* __restrict__ wv, const float* __restrict__ w1,
    const float* __restrict__ wo, const float* __restrict__ w2,
    const float* __restrict__ s2,
    uint16_t* __restrict__ WbigT, uint16_t* __restrict__ WfinT) {
  const float* in; uint16_t* out; int ostride, ocol; bool scale = false;
  switch (blockIdx.z) {
    case 0: in = wq; out = WbigT;                         ostride = 1024; ocol = 0;    break;
    case 1: in = wk; out = WbigT + (size_t)1024 * 1024;   ostride = 1024; ocol = 0;    break;
    case 2: in = wv; out = WbigT + (size_t)2048 * 1024;   ostride = 1024; ocol = 0;    break;
    case 3: in = w1; out = WbigT + (size_t)3072 * 1024;   ostride = 1024; ocol = 0; scale = true; break;
    case 4: in = wo; out = WfinT;                         ostride = 2048; ocol = 0;    break;
    default: in = w2; out = WfinT;                        ostride = 2048; ocol = 1024; break;
  }
  __shared__ float tile[32][33];
  const int c0 = blockIdx.x * 32, r0 = blockIdx.y * 32;
  const int tx = threadIdx.x & 31, ty = threadIdx.x >> 5;
  #pragma unroll
  for (int i = 0; i < 32; i += 8) {
    float v = in[(size_t)(r0 + ty + i) * 1024 + c0 + tx];
    if (scale) v *= s2[r0 + ty + i];
    tile[ty + i][tx] = v;
  }
  __syncthreads();
  #pragma unroll
  for (int i = 0; i < 32; i += 8)
    out[(size_t)(c0 + ty + i) * ostride + ocol + r0 + tx] = f2bf(tile[tx][ty + i]);
}

__global__ void bias_pack(const float* __restrict__ bq, const float* __restrict__ bk,
                          const float* __restrict__ bv, const float* __restrict__ bo,
                          const float* __restrict__ b2, float* __restrict__ biasAll,
                          float* __restrict__ bfin) {
  int i = blockIdx.x * 256 + threadIdx.x;  // 0..4095
  if (i < 1024) biasAll[i] = bq[i];
  else if (i < 2048) biasAll[i] = bk[i - 1024];
  else if (i < 3072) biasAll[i] = bv[i - 2048];
  else bfin[i - 3072] = bo[i - 3072] + b2[i - 3072];
}

// ---------------- column reductions for the LN2 fold:
// s2w1[n] = sum_k s2[k]*W1[k,n];  biasAll[3072+n] = sum_k o2[k]*W1[k,n] + b1[n]
__global__ __launch_bounds__(256) void colreduce(const float* __restrict__ W1,
    const float* __restrict__ s2, const float* __restrict__ o2,
    const float* __restrict__ b1, float* __restrict__ s2w1,
    float* __restrict__ biasg) {
  const int c = blockIdx.x * 128 + (threadIdx.x & 127);
  const int hh = threadIdx.x >> 7;  // 0 or 1
  float sa = 0.f, sb = 0.f;
  for (int k = hh * 512; k < (hh + 1) * 512; ++k) {
    const float w = W1[(size_t)k * 1024 + c];
    sa += s2[k] * w; sb += o2[k] * w;
  }
  __shared__ float pa[128], pb[128];
  if (hh == 1) { pa[threadIdx.x & 127] = sa; pb[threadIdx.x & 127] = sb; }
  __syncthreads();
  if (hh == 0) {
    s2w1[c] = sa + pa[threadIdx.x];
    biasg[c] = sb + pb[threadIdx.x] + b1[c];
  }
}

// ---------------- LN1: x -> h (bf16); also LN2 stats of h -> r2m2[row] = {rstd2, rstd2*mean2}
__global__ __launch_bounds__(256) void ln_kernel(
    const float* __restrict__ x,
    const float* __restrict__ s1, const float* __restrict__ o1,
    uint16_t* __restrict__ h, float2* __restrict__ r2m2) {
  const int row = blockIdx.x, tid = threadIdx.x;
  __shared__ float red[8];
  const float4 xv = ((const float4*)(x + (size_t)row * D_))[tid];
  float s = xv.x + xv.y + xv.z + xv.w;
  float ss = xv.x * xv.x + xv.y * xv.y + xv.z * xv.z + xv.w * xv.w;
  #pragma unroll
  for (int o = 32; o > 0; o >>= 1) { s += __shfl_down(s, o); ss += __shfl_down(ss, o); }
  if ((tid & 63) == 0) { red[tid >> 6] = s; red[4 + (tid >> 6)] = ss; }
  __syncthreads();
  s = red[0] + red[1] + red[2] + red[3];
  ss = red[4] + red[5] + red[6] + red[7];
  const float mean = s * (1.0f / D_);
  const float rstd = rsqrtf(ss * (1.0f / D_) - mean * mean + 1e-5f);
  const float4 s1v = ((const float4*)s1)[tid];
  const float4 o1v = ((const float4*)o1)[tid];
  float hv0 = (xv.x - mean) * rstd * s1v.x + o1v.x;
  float hv1 = (xv.y - mean) * rstd * s1v.y + o1v.y;
  float hv2 = (xv.z - mean) * rstd * s1v.z + o1v.z;
  float hv3 = (xv.w - mean) * rstd * s1v.w + o1v.w;
  ushort4 hu; hu.x = f2bf(hv0); hu.y = f2bf(hv1); hu.z = f2bf(hv2); hu.w = f2bf(hv3);
  ((ushort4*)(h + (size_t)row * D_))[tid] = hu;
  float sb = hv0 + hv1 + hv2 + hv3;
  float ssb = hv0 * hv0 + hv1 * hv1 + hv2 * hv2 + hv3 * hv3;
  #pragma unroll
  for (int o = 32; o > 0; o >>= 1) { sb += __shfl_down(sb, o); ssb += __shfl_down(ssb, o); }
  __syncthreads();  // red reuse safe
  if ((tid & 63) == 0) { red[tid >> 6] = sb; red[4 + (tid >> 6)] = ssb; }
  __syncthreads();
  if (tid == 0) {
    sb = red[0] + red[1] + red[2] + red[3];
    ssb = red[4] + red[5] + red[6] + red[7];
    const float mean2 = sb * (1.0f / D_);
    const float rstd2 = rsqrtf(ssb * (1.0f / D_) - mean2 * mean2 + 1e-5f);
    r2m2[row] = make_float2(rstd2, rstd2 * mean2);
  }
}

// ---------------- 256x256 bf16 GEMM, BK=64, K-half-slot pipeline (R5 core, best measured).
// MODE 1: QKV, N=3072 segs [q|k|v] (v -> vout);  MODE 2: FFN1-from-h with LN2 fold (+gelu)
// -> obf cols [2048,3072);  MODE 3: final (+bias+x residual) -> f32.
template <int MODE>
__global__ __launch_bounds__(512, 2) void gemm_kernel(
    const uint16_t* __restrict__ A, int lda,
    const uint16_t* __restrict__ Bt, int K,
    const float* __restrict__ bias,
    const int* __restrict__ labels,
    const float* __restrict__ arck,
    const float* __restrict__ arcv,
    const float* __restrict__ s2w1,
    const float2* __restrict__ r2m2,
    const float* __restrict__ xres,
    uint16_t* __restrict__ obf,
    uint16_t* __restrict__ vout,
    float* __restrict__ ofl) {
  __shared__ __align__(16) uint16_t Al[2][2][128 * 64];
  __shared__ __align__(16) uint16_t Bl[2][2][128 * 64];
  const int tid = threadIdx.x, lane = tid & 63, w = tid >> 6;
  const int oid = blockIdx.y * gridDim.x + blockIdx.x;
  const int nwg = gridDim.x * gridDim.y;
  const int lid = (oid & 7) * (nwg >> 3) + (oid >> 3);
  const int m0 = (lid / gridDim.x) * 256, n0 = (lid % gridDim.x) * 256;
  const int wm = w >> 2, wn = w & 3;
  const int fr = lane & 15, fk = lane >> 4;

  const int sr = tid >> 3, sc = tid & 7, scs = sc ^ (sr & 7);
  const size_t aRow = (size_t)(m0 + 2 * sr + (scs >> 2)) * lda + (scs & 3) * 8;
  const size_t bRow = (size_t)(n0 + 2 * sr + (scs >> 2)) * K + (scs & 3) * 8;
  const int dOff = sr * 64 + sc * 8;

  f32x4 acc[4][8];  // [ni][mj]
  const f32x4 z4 = {0.f, 0.f, 0.f, 0.f};
  #pragma unroll
  for (int i = 0; i < 4; i++)
    #pragma unroll
    for (int j = 0; j < 8; j++) acc[i][j] = z4;

#define ST_A(pp, kh, kt) do { \
    const uint16_t* s_ = A + aRow + (kt) + (kh) * 32; \
    async16(s_, &Al[pp][kh][dOff]); \
    async16(s_ + (size_t)128 * lda, &Al[pp][kh][dOff + 4096]); } while (0)
#define ST_B(pp, kh, kt) do { \
    const uint16_t* s_ = Bt + bRow + (kt) + (kh) * 32; \
    async16(s_, &Bl[pp][kh][dOff]); \
    async16(s_ + (size_t)128 * K, &Bl[pp][kh][dOff + 4096]); } while (0)
#define RD_A(pp, kh, ch) do { \
    _Pragma("unroll") \
    for (int mi = 0; mi < 4; ++mi) { \
      const int ml = wm * 128 + (ch) * 64 + mi * 16 + fr; \
      const int rr = ml >> 1; \
      const int cc = ((((ml & 1) << 2) | fk) ^ (rr & 7)); \
      afr[mi] = *(const bf16x8*)(&Al[pp][kh][rr * 64 + cc * 8]); \
    } } while (0)
#define RD_B(pp, kh) do { \
    _Pragma("unroll") \
    for (int ni = 0; ni < 4; ++ni) { \
      const int nl = wn * 64 + ni * 16 + fr; \
      const int rr = nl >> 1; \
      const int cc = ((((nl & 1) << 2) | fk) ^ (rr & 7)); \
      bfr[ni] = *(const bf16x8*)(&Bl[pp][kh][rr * 64 + cc * 8]); \
    } } while (0)
#define MM(ch) do { \
    __builtin_amdgcn_s_setprio(1); \
    _Pragma("unroll") \
    for (int ni = 0; ni < 4; ++ni) \
      _Pragma("unroll") \
      for (int mi = 0; mi < 4; ++mi) \
        acc[ni][(ch) * 4 + mi] = __builtin_amdgcn_mfma_f32_16x16x32_bf16( \
            bfr[ni], afr[mi], acc[ni][(ch) * 4 + mi], 0, 0, 0); \
    __builtin_amdgcn_s_setprio(0); } while (0)
#define BAR __builtin_amdgcn_s_barrier()

  ST_A(0, 0, 0); ST_B(0, 0, 0); ST_A(0, 1, 0); ST_B(0, 1, 0);
  asm volatile("s_waitcnt vmcnt(4)" ::: "memory");
  BAR;

  const int NT = K >> 6;
  for (int t = 0; t < NT; ++t) {
    const int p = t & 1, kt1 = (t + 1) << 6;
    const bool more = (t + 1 < NT);
    bf16x8 afr[4], bfr[4];
    RD_A(p, 0, 0); RD_B(p, 0);
    if (more) ST_A(p ^ 1, 0, kt1);
    BAR; MM(0); BAR;
    RD_A(p, 0, 1);
    if (more) {
      ST_B(p ^ 1, 0, kt1);
      asm volatile("s_waitcnt vmcnt(4)" ::: "memory");
    } else {
      asm volatile("s_waitcnt vmcnt(0)" ::: "memory");
    }
    BAR; MM(1); BAR;
    RD_A(p, 1, 0); RD_B(p, 1);
    if (more) ST_A(p ^ 1, 1, kt1);
    BAR; MM(0); BAR;
    RD_A(p, 1, 1);
    if (more) {
      ST_B(p ^ 1, 1, kt1);
      asm volatile("s_waitcnt vmcnt(4)" ::: "memory");
    }
    BAR; MM(1); BAR;
  }
#undef ST_A
#undef ST_B
#undef RD_A
#undef RD_B
#undef MM
#undef BAR

  // epilogue: lane fr owns row; 4 consecutive cols per reg-quad.
  const int seg = n0 >> 10;  // MODE 1: 0:q 1:k 2:v (block-uniform)
  #pragma unroll
  for (int mi = 0; mi < 8; ++mi) {
    const int row = m0 + wm * 128 + mi * 16 + fr;
    int lab = 0; float2 rm = make_float2(0.f, 0.f);
    if constexpr (MODE == 1) {
      if (seg >= 1) lab = labels[row];
    }
    if constexpr (MODE == 2) rm = r2m2[row];
    #pragma unroll
    for (int ni = 0; ni < 4; ++ni) {
      const int col0 = n0 + wn * 64 + ni * 16 + (fk << 2);
      const float4 b4 = *(const float4*)(bias + col0);
      float v0, v1, v2, v3;
      if constexpr (MODE == 1) {
        v0 = acc[ni][mi][0] + b4.x; v1 = acc[ni][mi][1] + b4.y;
        v2 = acc[ni][mi][2] + b4.z; v3 = acc[ni][mi][3] + b4.w;
        if (seg == 0) {
          v0 = elu1(v0); v1 = elu1(v1); v2 = elu1(v2); v3 = elu1(v3);
          ushort4 u; u.x = f2bf(v0); u.y = f2bf(v1); u.z = f2bf(v2); u.w = f2bf(v3);
          *(ushort4*)(obf + (size_t)row * 3072 + col0) = u;
        } else if (seg == 1) {
          const float4 ak = *(const float4*)(arck + lab * 64 + (col0 & 63));
          v0 = elu1(v0 + ak.x); v1 = elu1(v1 + ak.y); v2 = elu1(v2 + ak.z); v3 = elu1(v3 + ak.w);
          ushort4 u; u.x = f2bf(v0); u.y = f2bf(v1); u.z = f2bf(v2); u.w = f2bf(v3);
          *(ushort4*)(obf + (size_t)row * 3072 + col0) = u;
        } else {
          const float4 av = *(const float4*)(arcv + lab * 64 + (col0 & 63));
          v0 += av.x; v1 += av.y; v2 += av.z; v3 += av.w;
          ushort4 u; u.x = f2bf(v0); u.y = f2bf(v1); u.z = f2bf(v2); u.w = f2bf(v3);
          *(ushort4*)(vout + (size_t)row * 1024 + (col0 - 2048)) = u;
        }
      } else if constexpr (MODE == 2) {
        const float4 sw = *(const float4*)(s2w1 + col0);
        v0 = rm.x * acc[ni][mi][0] - rm.y * sw.x + b4.x;
        v1 = rm.x * acc[ni][mi][1] - rm.y * sw.y + b4.y;
        v2 = rm.x * acc[ni][mi][2] - rm.y * sw.z + b4.z;
        v3 = rm.x * acc[ni][mi][3] - rm.y * sw.w + b4.w;
        ushort4 u;
        u.x = f2bf(gelu_t(v0)); u.y = f2bf(gelu_t(v1));
        u.z = f2bf(gelu_t(v2)); u.w = f2bf(gelu_t(v3));
        *(ushort4*)(obf + (size_t)row * 3072 + 2048 + col0) = u;
      } else {
        v0 = acc[ni][mi][0] + b4.x; v1 = acc[ni][mi][1] + b4.y;
        v2 = acc[ni][mi][2] + b4.z; v3 = acc[ni][mi][3] + b4.w;
        const float4 xr = *(const float4*)(xres + (size_t)row * 1024 + col0);
        float4 o4; o4.x = v0 + xr.x; o4.y = v1 + xr.y; o4.z = v2 + xr.z; o4.w = v3 + xr.w;
        *(float4*)(ofl + (size_t)row * 1024 + col0) = o4;
      }
    }
  }
}

// ---------------- kv reduction: M[bh][i][j] = sum_t phi(k)[t,i]*v[t,j]; ksum[bh][i] = sum_t phi(k)[t,i]
__global__ __launch_bounds__(256) void kv_kernel(const uint16_t* __restrict__ qkv,
    const uint16_t* __restrict__ vbuf,
    float* __restrict__ Mst, float* __restrict__ ksum) {
  const int bh = blockIdx.y, sub = blockIdx.x;
  const int b = bh >> 4, hh = bh & 15;
  const int base = b * T_ + sub * 512;
  __shared__ __align__(16) float klds[64 * 64];
  __shared__ __align__(16) float vlds[64 * 64];
  const int tid = threadIdx.x;
  const int ti = tid >> 4, tj = tid & 15;
  const int i0 = ti * 4, j0 = tj * 4;
  float acc[4][4] = {};
  float kacc = 0.f;
  for (int cc = 0; cc < 8; cc++) {
    __syncthreads();
    #pragma unroll
    for (int p = 0; p < 4; p++) {
      const int t = p * 16 + ti;
      const int grow = base + cc * 64 + t;
      const uint2 ku = *(const uint2*)(qkv + (size_t)grow * 3072 + 1024 + hh * 64 + tj * 4);
      const uint2 vu = *(const uint2*)(vbuf + (size_t)grow * 1024 + hh * 64 + tj * 4);
      float* kd = klds + t * 64 + tj * 4;
      kd[0] = bf2f((uint16_t)ku.x); kd[1] = bf2f((uint16_t)(ku.x >> 16));
      kd[2] = bf2f((uint16_t)ku.y); kd[3] = bf2f((uint16_t)(ku.y >> 16));
      float* vd = vlds + t * 64 + tj * 4;
      vd[0] = bf2f((uint16_t)vu.x); vd[1] = bf2f((uint16_t)(vu.x >> 16));
      vd[2] = bf2f((uint16_t)vu.y); vd[3] = bf2f((uint16_t)(vu.y >> 16));
    }
    __syncthreads();
    #pragma unroll 8
    for (int t = 0; t < 64; t++) {
      const f32x4 ka = *(const f32x4*)(klds + t * 64 + i0);
      const f32x4 va = *(const f32x4*)(vlds + t * 64 + j0);
      #pragma unroll
      for (int ii = 0; ii < 4; ii++)
        #pragma unroll
        for (int jj = 0; jj < 4; jj++)
          acc[ii][jj] += ka[ii] * va[jj];
    }
    if (tid < 64) {
      #pragma unroll 8
      for (int t = 0; t < 64; t++) kacc += klds[t * 64 + tid];
    }
  }
  float* Mrow = Mst + (size_t)bh * 4096;
  #pragma unroll
  for (int ii = 0; ii < 4; ii++)
    #pragma unroll
    for (int jj = 0; jj < 4; jj++)
      atomicAdd(Mrow + (i0 + ii) * 64 + j0 + jj, acc[ii][jj]);
  if (tid < 64) atomicAdd(ksum + bh * 64 + tid, kacc);
}

// ---------------- attention apply: a[t, h*64+d] = (sum_k M[bh][d][k]*q[t,k]) / (q[t,:].ksum[bh])
__global__ __launch_bounds__(256) void attn_kernel(const uint16_t* __restrict__ qkv,
    const float* __restrict__ Mst, const float* __restrict__ ksum,
    uint16_t* __restrict__ aout) {
  const int bh = blockIdx.y, chunk = blockIdx.x;
  const int b = bh >> 4, hh = bh & 15;
  const int r0 = b * T_ + chunk * 128;
  __shared__ __align__(16) uint16_t qlds[128 * 64];
  __shared__ __align__(16) uint16_t Mlds[64 * 64];
  __shared__ float rinv[128];
  const int tid = threadIdx.x, lane = tid & 63, w = tid >> 6;
  #pragma unroll
  for (int j = 0; j < 4; j++) {
    const int c = w * 4 + j;
    const int rowl = c * 8 + (lane >> 3);
    async16(qkv + (size_t)(r0 + rowl) * 3072 + hh * 64 + (lane & 7) * 8, qlds + c * 512);
  }
  {
    const float4* Mp = (const float4*)(Mst + (size_t)bh * 4096);
    #pragma unroll
    for (int i = 0; i < 4; i++) {
      const float4 mv = Mp[tid + i * 256];
      ushort4 mu; mu.x = f2bf(mv.x); mu.y = f2bf(mv.y); mu.z = f2bf(mv.z); mu.w = f2bf(mv.w);
      *(ushort4*)(Mlds + (size_t)(tid + i * 256) * 4) = mu;
    }
  }
  const float ksv = ksum[bh * 64 + lane];
  __syncthreads();
  for (int i = 0; i < 32; i++) {
    const int t = w * 32 + i;
    float p = bf2f(qlds[t * 64 + lane]) * ksv;
    #pragma unroll
    for (int o = 32; o > 0; o >>= 1) p += __shfl_xor(p, o);
    if (lane == 0) rinv[t] = 1.0f / p;
  }
  __syncthreads();
  f32x4 acc[4][2];
  const f32x4 z4 = {0.f, 0.f, 0.f, 0.f};
  #pragma unroll
  for (int i = 0; i < 4; i++)
    #pragma unroll
    for (int j = 0; j < 2; j++) acc[i][j] = z4;
  #pragma unroll
  for (int ks = 0; ks < 2; ks++) {
    bf16x8 af[2], bfv[4];
    #pragma unroll
    for (int mi = 0; mi < 2; mi++)
      af[mi] = *(const bf16x8*)(qlds + (w * 32 + mi * 16 + (lane & 15)) * 64 + ks * 32 + (lane >> 4) * 8);
    #pragma unroll
    for (int ni = 0; ni < 4; ni++)
      bfv[ni] = *(const bf16x8*)(Mlds + (ni * 16 + (lane & 15)) * 64 + ks * 32 + (lane >> 4) * 8);
    #pragma unroll
    for (int ni = 0; ni < 4; ni++)
      #pragma unroll
      for (int mi = 0; mi < 2; mi++)
        acc[ni][mi] = __builtin_amdgcn_mfma_f32_16x16x32_bf16(bfv[ni], af[mi], acc[ni][mi], 0, 0, 0);
  }
  #pragma unroll
  for (int mi = 0; mi < 2; mi++) {
    const int t = w * 32 + mi * 16 + (lane & 15);
    const float rv = rinv[t];
    #pragma unroll
    for (int ni = 0; ni < 4; ni++) {
      const int d0 = ni * 16 + ((lane >> 4) << 2);
      ushort4 u;
      u.x = f2bf(acc[ni][mi][0] * rv);
      u.y = f2bf(acc[ni][mi][1] * rv);
      u.z = f2bf(acc[ni][mi][2] * rv);
      u.w = f2bf(acc[ni][mi][3] * rv);
      *(ushort4*)(aout + (size_t)(r0 + t) * 3072 + 1024 + hh * 64 + d0) = u;
    }
  }
}

extern "C" void kernel_launch(void* const* d_in, const int* in_sizes, int n_in,
                              void* d_out, int out_size, void* d_ws, size_t ws_size,
                              hipStream_t stream) {
  const float* x     = (const float*)d_in[0];
  const int*   labels= (const int*)d_in[1];
  const float* emb_k = (const float*)d_in[2];
  const float* emb_v = (const float*)d_in[3];
  const float* ln1_s = (const float*)d_in[4];
  const float* ln1_b = (const float*)d_in[5];
  const float* wq = (const float*)d_in[6];
  const float* bq = (const float*)d_in[7];
  const float* wk = (const float*)d_in[8];
  const float* bk = (const float*)d_in[9];
  const float* wv = (const float*)d_in[10];
  const float* bv = (const float*)d_in[11];
  const float* wo = (const float*)d_in[12];
  const float* bo = (const float*)d_in[13];
  const float* ln2_s = (const float*)d_in[14];
  const float* ln2_b = (const float*)d_in[15];
  const float* w1 = (const float*)d_in[16];
  const float* b1 = (const float*)d_in[17];
  const float* w2 = (const float*)d_in[18];
  const float* b2 = (const float*)d_in[19];
  float* out = (float*)d_out;
  char* ws = (char*)d_ws;

  // ws layout (bytes)
  uint16_t* qkv    = (uint16_t*)(ws);                 // [32768][3072] bf16: q|kphi->(a)|g
  uint16_t* WbigT  = (uint16_t*)(ws + 201326592);     // [4096][1024] = [Wq|Wk|Wv|W1s]^T
  uint16_t* WfinT  = (uint16_t*)(ws + 209715200);     // [1024][2048] = [Wo^T | W2^T]
  float*    biasAll= (float*)(ws + 213909504);        // [4096]: bq|bk|bv|(o2W1+b1)
  float*    bfin   = (float*)(ws + 213925888);        // [1024] = bo+b2
  float*    s2w1   = (float*)(ws + 213929984);        // [1024]
  float2*   r2m2   = (float2*)(ws + 213934080);       // [32768] {rstd2, rstd2*mean2}
  float*    Mst    = (float*)(ws + 214196224);        // [128][64][64]
  float*    ksumb  = (float*)(ws + 216293376);        // [128][64]

  // h lives in d_out[0:64MB]; v (bf16) in d_out[64MB:128MB]; final GEMM overwrites all.
  uint16_t* h    = (uint16_t*)d_out;
  uint16_t* vbuf = h + (size_t)BT_ * D_;

  const dim3 b256(256);
  transpose_pack6<<<dim3(32, 32, 6), b256, 0, stream>>>(wq, wk, wv, w1, wo, w2,
      ln2_s, WbigT, WfinT);
  bias_pack<<<16, b256, 0, stream>>>(bq, bk, bv, bo, b2, biasAll, bfin);
  colreduce<<<8, b256, 0, stream>>>(w1, ln2_s, ln2_b, b1, s2w1, biasAll + 3072);
  hipMemsetAsync(Mst, 0, 2097152 + 32768, stream);

  ln_kernel<<<BT_, b256, 0, stream>>>(x, ln1_s, ln1_b, h, r2m2);

  const dim3 b512(512);
  // QKV: [q|k|v] = h @ [Wq|Wk|Wv]; q,k -> qkv, v -> vbuf
  gemm_kernel<1><<<dim3(12, 128), b512, 0, stream>>>(h, 1024, WbigT, 1024, biasAll,
      labels, emb_k, emb_v, nullptr, nullptr, nullptr, qkv, vbuf, nullptr);
  // FFN1 from h with LN2 fold: g -> qkv cols [2048,3072)
  gemm_kernel<2><<<dim3(4, 128), b512, 0, stream>>>(h, 1024,
      WbigT + (size_t)3072 * 1024, 1024, biasAll + 3072,
      nullptr, nullptr, nullptr, s2w1, r2m2, nullptr, qkv, nullptr, nullptr);
  // kv state + ksum (v from vbuf)
  kv_kernel<<<dim3(8, 128), b256, 0, stream>>>(qkv, vbuf, Mst, ksumb);
  // attention apply -> a into qkv cols [1024,2048)
  attn_kernel<<<dim3(32, 128), b256, 0, stream>>>(qkv, Mst, ksumb, qkv);
  // final: [a|g] @ [Wo;W2] + (bo+b2) + x -> out (f32)
  gemm_kernel<3><<<dim3(4, 128), b512, 0, stream>>>(qkv + 1024, 3072, WfinT, 2048, bfin,
      nullptr, nullptr, nullptr, nullptr, nullptr, x, nullptr, nullptr, out);
}